// Round 1
// baseline (27.884 us; speedup 1.0000x reference)
//
#include <hip/hip_runtime.h>

#define SPECIAL_OFFSET 72      // 52 + NUM_BET_BINS(20)
#define NUM_SPECIAL 8
#define D_MODEL 256
#define NUM_CONTEXT 16
#define LN_EPS 1e-5f

// One 64-lane wave per token. Lane owns 4 consecutive channels (float4).
// Token id is wave-uniform -> branches are wave-uniform (no divergence).
// LayerNorm reduction = 6-step __shfl_xor across the wave.
__global__ __launch_bounds__(256, 2) void ContextEmbedding_35012573397647_kernel(
    const int*   __restrict__ token_ids,   // [N]
    const float* __restrict__ ctx_feat,    // [N, 16]
    const float* __restrict__ emb_table,   // [8, 256]
    const float* __restrict__ W_cls,       // [3, 256]
    const float* __restrict__ b_cls,       // [256]
    const float* __restrict__ g_cls,       // [256]
    const float* __restrict__ beta_cls,    // [256]
    const float* __restrict__ W_ctx,       // [16, 256]
    const float* __restrict__ b_ctx,       // [256]
    const float* __restrict__ g_ctx,       // [256]
    const float* __restrict__ beta_ctx,    // [256]
    float*       __restrict__ out,         // [N, 256]
    int n_tok)
{
    const int lane          = threadIdx.x & 63;
    const int wave_in_block = threadIdx.x >> 6;            // 0..3
    const int waves_total   = (gridDim.x * blockDim.x) >> 6;
    const int d0            = lane << 2;                   // channel base: lane*4

    int tok = blockIdx.x * (blockDim.x >> 6) + wave_in_block;
    for (; tok < n_tok; tok += waves_total) {
        const int tid = token_ids[tok];                    // wave-uniform

        float a0 = 0.f, a1 = 0.f, a2 = 0.f, a3 = 0.f;

        // --- special-token embedding lookup ---
        if (tid >= SPECIAL_OFFSET && tid < SPECIAL_OFFSET + NUM_SPECIAL) {
            const float4 e = *reinterpret_cast<const float4*>(
                &emb_table[(tid - SPECIAL_OFFSET) * D_MODEL + d0]);
            a0 = e.x; a1 = e.y; a2 = e.z; a3 = e.w;
        }

        // --- CLS MLP: Linear(3->256) -> LN -> ReLU ---
        if (tid == SPECIAL_OFFSET + 0) {
            const float x0 = ctx_feat[tok * NUM_CONTEXT + 0];
            const float x1 = ctx_feat[tok * NUM_CONTEXT + 1];
            const float x2 = ctx_feat[tok * NUM_CONTEXT + 2];
            const float4 w0 = *reinterpret_cast<const float4*>(&W_cls[0 * D_MODEL + d0]);
            const float4 w1 = *reinterpret_cast<const float4*>(&W_cls[1 * D_MODEL + d0]);
            const float4 w2 = *reinterpret_cast<const float4*>(&W_cls[2 * D_MODEL + d0]);
            const float4 bb = *reinterpret_cast<const float4*>(&b_cls[d0]);
            float h0 = fmaf(x0, w0.x, fmaf(x1, w1.x, fmaf(x2, w2.x, bb.x)));
            float h1 = fmaf(x0, w0.y, fmaf(x1, w1.y, fmaf(x2, w2.y, bb.y)));
            float h2 = fmaf(x0, w0.z, fmaf(x1, w1.z, fmaf(x2, w2.z, bb.z)));
            float h3 = fmaf(x0, w0.w, fmaf(x1, w1.w, fmaf(x2, w2.w, bb.w)));

            float s  = h0 + h1 + h2 + h3;
            float ss = h0 * h0 + h1 * h1 + h2 * h2 + h3 * h3;
            #pragma unroll
            for (int m = 1; m < 64; m <<= 1) {
                s  += __shfl_xor(s,  m, 64);
                ss += __shfl_xor(ss, m, 64);
            }
            const float mu  = s * (1.f / 256.f);
            const float var = ss * (1.f / 256.f) - mu * mu;
            const float inv = rsqrtf(var + LN_EPS);
            const float4 gg = *reinterpret_cast<const float4*>(&g_cls[d0]);
            const float4 be = *reinterpret_cast<const float4*>(&beta_cls[d0]);
            a0 += fmaxf((h0 - mu) * inv * gg.x + be.x, 0.f);
            a1 += fmaxf((h1 - mu) * inv * gg.y + be.y, 0.f);
            a2 += fmaxf((h2 - mu) * inv * gg.z + be.z, 0.f);
            a3 += fmaxf((h3 - mu) * inv * gg.w + be.w, 0.f);
        }

        // --- CONTEXT MLP: Linear(16->256) -> LN -> ReLU ---
        if (tid == SPECIAL_OFFSET + 1) {
            const float4 bb = *reinterpret_cast<const float4*>(&b_ctx[d0]);
            float h0 = bb.x, h1 = bb.y, h2 = bb.z, h3 = bb.w;
            #pragma unroll
            for (int k = 0; k < NUM_CONTEXT; ++k) {
                const float xk = ctx_feat[tok * NUM_CONTEXT + k];   // uniform broadcast
                const float4 w = *reinterpret_cast<const float4*>(&W_ctx[k * D_MODEL + d0]);
                h0 = fmaf(xk, w.x, h0);
                h1 = fmaf(xk, w.y, h1);
                h2 = fmaf(xk, w.z, h2);
                h3 = fmaf(xk, w.w, h3);
            }
            float s  = h0 + h1 + h2 + h3;
            float ss = h0 * h0 + h1 * h1 + h2 * h2 + h3 * h3;
            #pragma unroll
            for (int m = 1; m < 64; m <<= 1) {
                s  += __shfl_xor(s,  m, 64);
                ss += __shfl_xor(ss, m, 64);
            }
            const float mu  = s * (1.f / 256.f);
            const float var = ss * (1.f / 256.f) - mu * mu;
            const float inv = rsqrtf(var + LN_EPS);
            const float4 gg = *reinterpret_cast<const float4*>(&g_ctx[d0]);
            const float4 be = *reinterpret_cast<const float4*>(&beta_ctx[d0]);
            a0 += fmaxf((h0 - mu) * inv * gg.x + be.x, 0.f);
            a1 += fmaxf((h1 - mu) * inv * gg.y + be.y, 0.f);
            a2 += fmaxf((h2 - mu) * inv * gg.z + be.z, 0.f);
            a3 += fmaxf((h3 - mu) * inv * gg.w + be.w, 0.f);
        }

        float4 o; o.x = a0; o.y = a1; o.z = a2; o.w = a3;
        *reinterpret_cast<float4*>(&out[tok * D_MODEL + d0]) = o;
    }
}

extern "C" void kernel_launch(void* const* d_in, const int* in_sizes, int n_in,
                              void* d_out, int out_size, void* d_ws, size_t ws_size,
                              hipStream_t stream) {
    const int*   token_ids = (const int*)  d_in[0];
    const float* ctx_feat  = (const float*)d_in[1];
    const float* emb_table = (const float*)d_in[2];
    const float* W_cls     = (const float*)d_in[3];
    const float* b_cls     = (const float*)d_in[4];
    const float* g_cls     = (const float*)d_in[5];
    const float* beta_cls  = (const float*)d_in[6];
    const float* W_ctx     = (const float*)d_in[7];
    const float* b_ctx     = (const float*)d_in[8];
    const float* g_ctx     = (const float*)d_in[9];
    const float* beta_ctx  = (const float*)d_in[10];
    float* out = (float*)d_out;

    const int n_tok = in_sizes[0];                 // 128*1024 = 131072
    const int block = 256;                         // 4 waves/block, 1 wave/token
    const int waves_needed = n_tok;                // one wave per token
    int grid = (waves_needed + 3) / 4;             // blocks if fully unrolled
    if (grid > 2048) grid = 2048;                  // cap + grid-stride (G11)

    ContextEmbedding_35012573397647_kernel<<<grid, block, 0, stream>>>(
        token_ids, ctx_feat, emb_table,
        W_cls, b_cls, g_cls, beta_cls,
        W_ctx, b_ctx, g_ctx, beta_ctx,
        out, n_tok);
}